// Round 1
// baseline (532.230 us; speedup 1.0000x reference)
//
#include <hip/hip_runtime.h>
#include <hip/hip_bf16.h>

#define B_ 128
#define T_ 512
#define L_ 256

typedef _Float16 h2 __attribute__((ext_vector_type(2)));

__device__ __forceinline__ float dot2f16(unsigned a, unsigned b, float c) {
#if __has_builtin(__builtin_amdgcn_fdot2)
    return __builtin_amdgcn_fdot2(__builtin_bit_cast(h2, a),
                                  __builtin_bit_cast(h2, b), c, false);
#else
    h2 ha = __builtin_bit_cast(h2, a), hb = __builtin_bit_cast(h2, b);
    return c + (float)ha.x * (float)hb.x + (float)ha.y * (float)hb.y;
#endif
}

// ---------------------------------------------------------------------------
// Kernel A: ET[m][l] = exp(trans[l][m])  (transposed, f16)
// ---------------------------------------------------------------------------
__global__ __launch_bounds__(256) void k_exptrans(const float* __restrict__ trans,
                                                  _Float16* __restrict__ ET) {
    int m = blockIdx.x;   // 256 blocks
    int l = threadIdx.x;  // 256 threads
    ET[m * L_ + l] = (_Float16)__expf(trans[l * L_ + m]);
}

// ---------------------------------------------------------------------------
// Kernel B: extract labels from one-hot y_true. One wave per (b,t) row.
// ---------------------------------------------------------------------------
__global__ __launch_bounds__(256) void k_labels(const float* __restrict__ y_true,
                                                int* __restrict__ labels) {
    int wid = threadIdx.x >> 6, lane = threadIdx.x & 63;
    int r = blockIdx.x * 4 + wid;                    // r in [0, B*T)
    const float4* row = (const float4*)(y_true + (size_t)r * L_);
    float4 v = row[lane];                            // coalesced 1 KiB/wave
    int loc = -1;
    if (v.x > 0.5f) loc = lane * 4 + 0;
    if (v.y > 0.5f) loc = lane * 4 + 1;
    if (v.z > 0.5f) loc = lane * 4 + 2;
    if (v.w > 0.5f) loc = lane * 4 + 3;
    unsigned long long m = __ballot(loc >= 0);
    int src = __ffsll(m) - 1;
    int lab = __shfl(loc, src, 64);
    if (lane == 0) labels[r] = lab;
}

// ---------------------------------------------------------------------------
// Kernel C: path_score[b] = sum_t y_pre[b,t,lab] + sum_t trans[lab_t, lab_{t+1}]
// ---------------------------------------------------------------------------
__global__ __launch_bounds__(256) void k_path(const float* __restrict__ y_pre,
                                              const float* __restrict__ trans,
                                              const int* __restrict__ labels,
                                              float* __restrict__ path) {
    int b = blockIdx.x, tid = threadIdx.x;
    const int* lb = labels + b * T_;
    float acc = 0.f;
    for (int t = tid; t < T_; t += 256) {
        int l1 = lb[t];
        acc += y_pre[((size_t)b * T_ + t) * L_ + l1];
        if (t + 1 < T_) acc += trans[l1 * L_ + lb[t + 1]];
    }
#pragma unroll
    for (int off = 1; off < 64; off <<= 1) acc += __shfl_xor(acc, off, 64);
    __shared__ float red[4];
    int wid = tid >> 6, lane = tid & 63;
    if (lane == 0) red[wid] = acc;
    __syncthreads();
    if (tid == 0) path[b] = red[0] + red[1] + red[2] + red[3];
}

// ---------------------------------------------------------------------------
// Kernel D: forward recursion. One block per batch; thread m owns state s[m]
// and keeps its ET row (256 f16 = 128 VGPRs) in registers.
// ---------------------------------------------------------------------------
__global__ __launch_bounds__(256) void k_forward(const float* __restrict__ y_pre,
                                                 const _Float16* __restrict__ ET,
                                                 const float* __restrict__ path,
                                                 float* __restrict__ out) {
    int b = blockIdx.x, m = threadIdx.x;
    int wid = m >> 6, lane = m & 63;
    const float* yp = y_pre + (size_t)b * T_ * L_;

    // ET row m -> 32 x uint4 = 128 VGPRs (static indices => register file)
    uint4 ROW[32];
    const uint4* rp = (const uint4*)(ET + (size_t)m * L_);
#pragma unroll
    for (int j = 0; j < 32; ++j) ROW[j] = rp[j];

    __shared__ alignas(16) _Float16 ph[L_];
    __shared__ float red[4];

    float s = yp[m];            // init = y_pre[b,0,:]
    float emit = yp[L_ + m];    // emit for t=1 (prefetched)

    for (int t = 1; t < T_; ++t) {
        // prefetch next emit (redundant clamp on last iter)
        float emit_nx = yp[(size_t)(t + 1 < T_ ? t + 1 : T_ - 1) * L_ + m];

        // block max of state
        float v = s;
#pragma unroll
        for (int off = 1; off < 64; off <<= 1) v = fmaxf(v, __shfl_xor(v, off, 64));
        if (lane == 0) red[wid] = v;
        __syncthreads();
        float M = fmaxf(fmaxf(red[0], red[1]), fmaxf(red[2], red[3]));

        ph[m] = (_Float16)__expf(s - M);   // p[m] in (0,1]
        __syncthreads();

        // dot: sum_l p[l] * ET[m][l], f16 dot2, 4-way accumulators
        const uint4* pp = (const uint4*)ph;
        float a0 = 0.f, a1 = 0.f, a2 = 0.f, a3 = 0.f;
#pragma unroll
        for (int j = 0; j < 32; ++j) {
            uint4 P = pp[j];   // LDS broadcast read (uniform addr)
            a0 = dot2f16(P.x, ROW[j].x, a0);
            a1 = dot2f16(P.y, ROW[j].y, a1);
            a2 = dot2f16(P.z, ROW[j].z, a2);
            a3 = dot2f16(P.w, ROW[j].w, a3);
        }
        float sum = (a0 + a1) + (a2 + a3);
        s = M + __logf(sum) + emit;
        emit = emit_nx;
    }

    // final logsumexp over m
    float v = s;
#pragma unroll
    for (int off = 1; off < 64; off <<= 1) v = fmaxf(v, __shfl_xor(v, off, 64));
    if (lane == 0) red[wid] = v;
    __syncthreads();
    float M = fmaxf(fmaxf(red[0], red[1]), fmaxf(red[2], red[3]));
    float e = __expf(s - M);
    v = e;
#pragma unroll
    for (int off = 1; off < 64; off <<= 1) v += __shfl_xor(v, off, 64);
    __syncthreads();   // protect red[] reuse
    if (lane == 0) red[wid] = v;
    __syncthreads();
    if (m == 0) out[b] = M + __logf(red[0] + red[1] + red[2] + red[3]) - path[b];
}

// ---------------------------------------------------------------------------
extern "C" void kernel_launch(void* const* d_in, const int* in_sizes, int n_in,
                              void* d_out, int out_size, void* d_ws, size_t ws_size,
                              hipStream_t stream) {
    const float* y_true = (const float*)d_in[0];
    const float* y_pre  = (const float*)d_in[1];
    const float* trans  = (const float*)d_in[2];
    float* out = (float*)d_out;

    char* ws = (char*)d_ws;
    _Float16* ET = (_Float16*)ws;                         // 128 KiB
    int* labels  = (int*)(ws + 131072);                   // 256 KiB
    float* path  = (float*)(ws + 131072 + 262144);        // 512 B

    hipLaunchKernelGGL(k_exptrans, dim3(L_), dim3(L_), 0, stream, trans, ET);
    hipLaunchKernelGGL(k_labels, dim3(B_ * T_ / 4), dim3(256), 0, stream, y_true, labels);
    hipLaunchKernelGGL(k_path, dim3(B_), dim3(256), 0, stream, y_pre, trans, labels, path);
    hipLaunchKernelGGL(k_forward, dim3(B_), dim3(256), 0, stream, y_pre, ET, path, out);
}

// Round 2
// 467.455 us; speedup vs baseline: 1.1386x; 1.1386x over previous
//
#include <hip/hip_runtime.h>
#include <hip/hip_bf16.h>

#define B_ 128
#define T_ 512
#define L_ 256

typedef _Float16 h2 __attribute__((ext_vector_type(2)));

__device__ __forceinline__ float dot2f16(unsigned a, unsigned b, float c) {
#if __has_builtin(__builtin_amdgcn_fdot2)
    return __builtin_amdgcn_fdot2(__builtin_bit_cast(h2, a),
                                  __builtin_bit_cast(h2, b), c, false);
#else
    h2 ha = __builtin_bit_cast(h2, a), hb = __builtin_bit_cast(h2, b);
    return c + (float)ha.x * (float)hb.x + (float)ha.y * (float)hb.y;
#endif
}

// ---------------------------------------------------------------------------
// Kernel A: ET[m][l] = exp(trans[l][m])  (transposed, f16)
// ---------------------------------------------------------------------------
__global__ __launch_bounds__(256) void k_exptrans(const float* __restrict__ trans,
                                                  _Float16* __restrict__ ET) {
    int m = blockIdx.x;   // 256 blocks
    int l = threadIdx.x;  // 256 threads
    ET[m * L_ + l] = (_Float16)__expf(trans[l * L_ + m]);
}

// ---------------------------------------------------------------------------
// Kernel B: extract labels from one-hot y_true. One wave per (b,t) row.
// ---------------------------------------------------------------------------
__global__ __launch_bounds__(256) void k_labels(const float* __restrict__ y_true,
                                                int* __restrict__ labels) {
    int wid = threadIdx.x >> 6, lane = threadIdx.x & 63;
    int r = blockIdx.x * 4 + wid;                    // r in [0, B*T)
    const float4* row = (const float4*)(y_true + (size_t)r * L_);
    float4 v = row[lane];                            // coalesced 1 KiB/wave
    int loc = -1;
    if (v.x > 0.5f) loc = lane * 4 + 0;
    if (v.y > 0.5f) loc = lane * 4 + 1;
    if (v.z > 0.5f) loc = lane * 4 + 2;
    if (v.w > 0.5f) loc = lane * 4 + 3;
    unsigned long long m = __ballot(loc >= 0);
    int src = __ffsll(m) - 1;
    int lab = __shfl(loc, src, 64);
    if (lane == 0) labels[r] = lab;
}

// ---------------------------------------------------------------------------
// Kernel C: path_score[b] = sum_t y_pre[b,t,lab] + sum_t trans[lab_t, lab_{t+1}]
// ---------------------------------------------------------------------------
__global__ __launch_bounds__(256) void k_path(const float* __restrict__ y_pre,
                                              const float* __restrict__ trans,
                                              const int* __restrict__ labels,
                                              float* __restrict__ path) {
    int b = blockIdx.x, tid = threadIdx.x;
    const int* lb = labels + b * T_;
    float acc = 0.f;
    for (int t = tid; t < T_; t += 256) {
        int l1 = lb[t];
        acc += y_pre[((size_t)b * T_ + t) * L_ + l1];
        if (t + 1 < T_) acc += trans[l1 * L_ + lb[t + 1]];
    }
#pragma unroll
    for (int off = 1; off < 64; off <<= 1) acc += __shfl_xor(acc, off, 64);
    __shared__ float red[4];
    int wid = tid >> 6, lane = tid & 63;
    if (lane == 0) red[wid] = acc;
    __syncthreads();
    if (tid == 0) path[b] = red[0] + red[1] + red[2] + red[3];
}

// ---------------------------------------------------------------------------
// Kernel D: forward recursion. One block per batch; thread m owns state s[m]
// and keeps its ET row (256 f16 = 128 VGPRs) in registers.
// __launch_bounds__(256,1): only 1 wave/SIMD ever runs (128 blocks, 1/CU) —
// allow up to 512 VGPRs so ROW[] is NOT demoted to per-step L2 re-loads.
// Lag-1 max normalization: exp uses previous step's max (bias -2 guards f16
// overflow); the 6-shuffle max reduce overlaps with the dot product.
// ---------------------------------------------------------------------------
__global__ __launch_bounds__(256, 1) void k_forward(const float* __restrict__ y_pre,
                                                    const _Float16* __restrict__ ET,
                                                    const float* __restrict__ path,
                                                    float* __restrict__ out) {
    int b = blockIdx.x, m = threadIdx.x;
    int wid = m >> 6, lane = m & 63;
    const float* yp = y_pre + (size_t)b * T_ * L_;

    // ET row m -> 32 x uint4 = 128 VGPRs (static indices => register file)
    uint4 ROW[32];
    const uint4* rp = (const uint4*)(ET + (size_t)m * L_);
#pragma unroll
    for (int j = 0; j < 32; ++j) ROW[j] = rp[j];

    __shared__ alignas(16) _Float16 ph[L_];
    __shared__ float red[4];

    float s = yp[m];            // init = y_pre[b,0,:]
    float emit = yp[L_ + m];    // emit for t=1 (prefetched)

    // initial block max (exact, once)
    {
        float v = s;
#pragma unroll
        for (int off = 1; off < 64; off <<= 1) v = fmaxf(v, __shfl_xor(v, off, 64));
        if (lane == 0) red[wid] = v;
        __syncthreads();
    }
    float M_prev = fmaxf(fmaxf(red[0], red[1]), fmaxf(red[2], red[3]));
    __syncthreads();

    for (int t = 1; t < T_; ++t) {
        float emit_nx = yp[(size_t)(t + 1 < T_ ? t + 1 : T_ - 1) * L_ + m];

        float Mb = M_prev + 2.0f;              // overflow-guard bias
        ph[m] = (_Float16)__expf(s - Mb);      // p[m], bounded ~e^9 worst case
        __syncthreads();                       // barrier 1: p visible

        // dot: sum_l p[l] * ET[m][l]  (f16 dot2, 4 accumulators)
        const uint4* pp = (const uint4*)ph;
        float a0 = 0.f, a1 = 0.f, a2 = 0.f, a3 = 0.f;
#pragma unroll
        for (int j = 0; j < 32; ++j) {
            uint4 P = pp[j];   // LDS broadcast (uniform addr)
            a0 = dot2f16(P.x, ROW[j].x, a0);
            a1 = dot2f16(P.y, ROW[j].y, a1);
            a2 = dot2f16(P.z, ROW[j].z, a2);
            a3 = dot2f16(P.w, ROW[j].w, a3);
        }

        // overlapped: block max of CURRENT s, consumed next step
        {
            float v = s;
#pragma unroll
            for (int off = 1; off < 64; off <<= 1) v = fmaxf(v, __shfl_xor(v, off, 64));
            if (lane == 0) red[wid] = v;
        }

        float sum = (a0 + a1) + (a2 + a3);
        s = Mb + __logf(sum) + emit;
        emit = emit_nx;
        __syncthreads();                       // barrier 2: red + ph-drain
        M_prev = fmaxf(fmaxf(red[0], red[1]), fmaxf(red[2], red[3]));
    }

    // final logsumexp over m
    __syncthreads();
    float v = s;
#pragma unroll
    for (int off = 1; off < 64; off <<= 1) v = fmaxf(v, __shfl_xor(v, off, 64));
    if (lane == 0) red[wid] = v;
    __syncthreads();
    float M = fmaxf(fmaxf(red[0], red[1]), fmaxf(red[2], red[3]));
    float e = __expf(s - M);
    v = e;
#pragma unroll
    for (int off = 1; off < 64; off <<= 1) v += __shfl_xor(v, off, 64);
    __syncthreads();   // protect red[] reuse
    if (lane == 0) red[wid] = v;
    __syncthreads();
    if (m == 0) out[b] = M + __logf(red[0] + red[1] + red[2] + red[3]) - path[b];
}

// ---------------------------------------------------------------------------
extern "C" void kernel_launch(void* const* d_in, const int* in_sizes, int n_in,
                              void* d_out, int out_size, void* d_ws, size_t ws_size,
                              hipStream_t stream) {
    const float* y_true = (const float*)d_in[0];
    const float* y_pre  = (const float*)d_in[1];
    const float* trans  = (const float*)d_in[2];
    float* out = (float*)d_out;

    char* ws = (char*)d_ws;
    _Float16* ET = (_Float16*)ws;                         // 128 KiB
    int* labels  = (int*)(ws + 131072);                   // 256 KiB
    float* path  = (float*)(ws + 131072 + 262144);        // 512 B

    hipLaunchKernelGGL(k_exptrans, dim3(L_), dim3(L_), 0, stream, trans, ET);
    hipLaunchKernelGGL(k_labels, dim3(B_ * T_ / 4), dim3(256), 0, stream, y_true, labels);
    hipLaunchKernelGGL(k_path, dim3(B_), dim3(256), 0, stream, y_pre, trans, labels, path);
    hipLaunchKernelGGL(k_forward, dim3(B_), dim3(256), 0, stream, y_pre, ET, path, out);
}

// Round 3
// 424.899 us; speedup vs baseline: 1.2526x; 1.1002x over previous
//
#include <hip/hip_runtime.h>
#include <hip/hip_bf16.h>

#define B_ 128
#define T_ 512
#define L_ 256

// v_dot2_f32_bf16: D = S0.bf16[0]*S1.bf16[0] + S0.bf16[1]*S1.bf16[1] + S2
__device__ __forceinline__ float dot2bf16(unsigned a, unsigned b, float c) {
    float d;
    asm("v_dot2_f32_bf16 %0, %1, %2, %3" : "=v"(d) : "v"(a), "v"(b), "v"(c));
    return d;
}

__device__ __forceinline__ unsigned short f2bf(float x) {  // RNE f32->bf16
    unsigned u = __builtin_bit_cast(unsigned, x);
    return (unsigned short)((u + 0x7fff + ((u >> 16) & 1)) >> 16);
}

// ---------------------------------------------------------------------------
// Kernel A: ETg[m][l] = bf16(exp(trans[l][m]))  (transposed)
// ---------------------------------------------------------------------------
__global__ __launch_bounds__(256) void k_exptrans(const float* __restrict__ trans,
                                                  unsigned short* __restrict__ ETg) {
    int m = blockIdx.x, l = threadIdx.x;
    ETg[m * L_ + l] = f2bf(__expf(trans[l * L_ + m]));
}

// ---------------------------------------------------------------------------
// Kernel B: labels from one-hot y_true (one wave per row)
// ---------------------------------------------------------------------------
__global__ __launch_bounds__(256) void k_labels(const float* __restrict__ y_true,
                                                int* __restrict__ labels) {
    int wid = threadIdx.x >> 6, lane = threadIdx.x & 63;
    int r = blockIdx.x * 4 + wid;
    const float4* row = (const float4*)(y_true + (size_t)r * L_);
    float4 v = row[lane];
    int loc = -1;
    if (v.x > 0.5f) loc = lane * 4 + 0;
    if (v.y > 0.5f) loc = lane * 4 + 1;
    if (v.z > 0.5f) loc = lane * 4 + 2;
    if (v.w > 0.5f) loc = lane * 4 + 3;
    unsigned long long m = __ballot(loc >= 0);
    int src = __ffsll(m) - 1;
    int lab = __shfl(loc, src, 64);
    if (lane == 0) labels[r] = lab;
}

// ---------------------------------------------------------------------------
// Kernel C: path_score
// ---------------------------------------------------------------------------
__global__ __launch_bounds__(256) void k_path(const float* __restrict__ y_pre,
                                              const float* __restrict__ trans,
                                              const int* __restrict__ labels,
                                              float* __restrict__ path) {
    int b = blockIdx.x, tid = threadIdx.x;
    const int* lb = labels + b * T_;
    float acc = 0.f;
    for (int t = tid; t < T_; t += 256) {
        int l1 = lb[t];
        acc += y_pre[((size_t)b * T_ + t) * L_ + l1];
        if (t + 1 < T_) acc += trans[l1 * L_ + lb[t + 1]];
    }
#pragma unroll
    for (int off = 1; off < 64; off <<= 1) acc += __shfl_xor(acc, off, 64);
    __shared__ float red[4];
    int wid = tid >> 6, lane = tid & 63;
    if (lane == 0) red[wid] = acc;
    __syncthreads();
    if (tid == 0) path[b] = red[0] + red[1] + red[2] + red[3];
}

// ---------------------------------------------------------------------------
// Kernel D: forward recursion, 4-way l-split.
// Thread (c=wave, i=lane) owns s[64c+i]; holds ET rows {i,i+64,i+128,i+192},
// l-chunk [64c,64c+64) in 128 VGPRs (bf16). Per step it reads only its 128-B
// p-chunk (8 uniform b128) and exchanges 4 f32 partials per owned row through
// a small padded LDS array. Normalizer: sampled lag-2 (s[0] two steps ago) —
// safe in bf16 (range=f32), no per-step max reduce on the critical path.
// ---------------------------------------------------------------------------
__global__ __launch_bounds__(256, 1) void k_forward(const float* __restrict__ yp_all,
                                                    const unsigned short* __restrict__ ETg,
                                                    const float* __restrict__ path,
                                                    float* __restrict__ out) {
    int b = blockIdx.x, tid = threadIdx.x;
    int c = tid >> 6;          // wave id = l-chunk
    int i = tid & 63;          // lane
    int m_own = (c << 6) | i;
    const float* yp = yp_all + (size_t)b * T_ * L_;

    // 4 row-chunks -> 32 uint4 = 128 VGPRs
    uint4 R[4][8];
#pragma unroll
    for (int r = 0; r < 4; ++r) {
        const uint4* src = (const uint4*)(ETg + (size_t)(i + 64 * r) * L_ + 64 * c);
#pragma unroll
        for (int j = 0; j < 8; ++j) R[r][j] = src[j];
    }
    // opaque defs: forbid rematerialization/demotion of R
#pragma unroll
    for (int r = 0; r < 4; ++r)
#pragma unroll
        for (int j = 0; j < 8; ++j)
            asm("" : "+v"(R[r][j].x), "+v"(R[r][j].y), "+v"(R[r][j].z), "+v"(R[r][j].w));

    __shared__ unsigned short ph[2][L_];   // p (bf16), double-buffered
    __shared__ float pj[L_ * 5];           // partials, padded stride 5 dwords
    __shared__ float red[4];
    __shared__ float nmr[2];               // sampled normalizer, 2 slots

    float s = yp[m_own];                   // s_0 = y_pre[b,0,:]

    {   // exact initial max (once)
        float v = s;
#pragma unroll
        for (int off = 1; off < 64; off <<= 1) v = fmaxf(v, __shfl_xor(v, off, 64));
        if (i == 0) red[c] = v;
        __syncthreads();
        if (tid == 0) {
            float M = fmaxf(fmaxf(red[0], red[1]), fmaxf(red[2], red[3]));
            nmr[0] = M; nmr[1] = M;
        }
        __syncthreads();
    }

    float emit = yp[L_ + m_own];           // emit for t=1

    for (int t = 1; t < T_; ++t) {
        // ---- phase A ----
        float N = nmr[t & 1];              // broadcast read (lag-2 sample)
        float emit_nx = yp[(size_t)(t + 1 < T_ ? t + 1 : T_ - 1) * L_ + m_own];
        ph[t & 1][m_own] = f2bf(__expf(s - N));
        __syncthreads();                   // barrier 1: p visible

        // ---- phase B: 4 partial dots over own l-chunk ----
        const uint4* P = (const uint4*)(&ph[t & 1][c << 6]);
        float a0 = 0, a1 = 0, a2 = 0, a3 = 0;
        float b0 = 0, b1 = 0, b2 = 0, b3 = 0;
#pragma unroll
        for (int j = 0; j < 8; ++j) {
            uint4 Pv = P[j];               // uniform b128 (128-B chunk)
            a0 = dot2bf16(Pv.x, R[0][j].x, a0); b0 = dot2bf16(Pv.y, R[0][j].y, b0);
            a0 = dot2bf16(Pv.z, R[0][j].z, a0); b0 = dot2bf16(Pv.w, R[0][j].w, b0);
            a1 = dot2bf16(Pv.x, R[1][j].x, a1); b1 = dot2bf16(Pv.y, R[1][j].y, b1);
            a1 = dot2bf16(Pv.z, R[1][j].z, a1); b1 = dot2bf16(Pv.w, R[1][j].w, b1);
            a2 = dot2bf16(Pv.x, R[2][j].x, a2); b2 = dot2bf16(Pv.y, R[2][j].y, b2);
            a2 = dot2bf16(Pv.z, R[2][j].z, a2); b2 = dot2bf16(Pv.w, R[2][j].w, b2);
            a3 = dot2bf16(Pv.x, R[3][j].x, a3); b3 = dot2bf16(Pv.y, R[3][j].y, b3);
            a3 = dot2bf16(Pv.z, R[3][j].z, a3); b3 = dot2bf16(Pv.w, R[3][j].w, b3);
        }
        pj[(i      ) * 5 + c] = a0 + b0;
        pj[(i +  64) * 5 + c] = a1 + b1;
        pj[(i + 128) * 5 + c] = a2 + b2;
        pj[(i + 192) * 5 + c] = a3 + b3;
        __syncthreads();                   // barrier 2: partials visible

        // ---- phase C: combine, advance state ----
        int base = m_own * 5;
        float sum = (pj[base] + pj[base + 1]) + (pj[base + 2] + pj[base + 3]);
        s = N + __logf(sum) + emit;
        emit = emit_nx;
        if (tid == 0) nmr[t & 1] = s;      // sample for step t+2
    }

    // final logsumexp over m
    __syncthreads();
    float v = s;
#pragma unroll
    for (int off = 1; off < 64; off <<= 1) v = fmaxf(v, __shfl_xor(v, off, 64));
    if (i == 0) red[c] = v;
    __syncthreads();
    float M = fmaxf(fmaxf(red[0], red[1]), fmaxf(red[2], red[3]));
    float e = __expf(s - M);
    v = e;
#pragma unroll
    for (int off = 1; off < 64; off <<= 1) v += __shfl_xor(v, off, 64);
    __syncthreads();
    if (i == 0) red[c] = v;
    __syncthreads();
    if (tid == 0) out[b] = M + __logf(red[0] + red[1] + red[2] + red[3]) - path[b];
}

// ---------------------------------------------------------------------------
extern "C" void kernel_launch(void* const* d_in, const int* in_sizes, int n_in,
                              void* d_out, int out_size, void* d_ws, size_t ws_size,
                              hipStream_t stream) {
    const float* y_true = (const float*)d_in[0];
    const float* y_pre  = (const float*)d_in[1];
    const float* trans  = (const float*)d_in[2];
    float* out = (float*)d_out;

    char* ws = (char*)d_ws;
    unsigned short* ETg = (unsigned short*)ws;            // 128 KiB
    int* labels = (int*)(ws + 131072);                    // 256 KiB
    float* path = (float*)(ws + 131072 + 262144);         // 512 B

    hipLaunchKernelGGL(k_exptrans, dim3(L_), dim3(L_), 0, stream, trans, ETg);
    hipLaunchKernelGGL(k_labels, dim3(B_ * T_ / 4), dim3(256), 0, stream, y_true, labels);
    hipLaunchKernelGGL(k_path, dim3(B_), dim3(256), 0, stream, y_pre, trans, labels, path);
    hipLaunchKernelGGL(k_forward, dim3(B_), dim3(256), 0, stream, y_pre, ETg, path, out);
}

// Round 4
// 395.770 us; speedup vs baseline: 1.3448x; 1.0736x over previous
//
#include <hip/hip_runtime.h>
#include <hip/hip_bf16.h>

#define B_ 128
#define T_ 512
#define L_ 256

// v_dot2_f32_bf16: D = S0.bf16[0]*S1.bf16[0] + S0.bf16[1]*S1.bf16[1] + S2
__device__ __forceinline__ float dot2bf16(unsigned a, unsigned b, float c) {
    float d;
    asm("v_dot2_f32_bf16 %0, %1, %2, %3" : "=v"(d) : "v"(a), "v"(b), "v"(c));
    return d;
}

__device__ __forceinline__ unsigned short f2bf(float x) {  // RNE f32->bf16
    unsigned u = __builtin_bit_cast(unsigned, x);
    return (unsigned short)((u + 0x7fff + ((u >> 16) & 1)) >> 16);
}

// ---------------------------------------------------------------------------
// Kernel A: ETg[m][l] = bf16(exp(trans[l][m]))  (transposed)
// ---------------------------------------------------------------------------
__global__ __launch_bounds__(256) void k_exptrans(const float* __restrict__ trans,
                                                  unsigned short* __restrict__ ETg) {
    int m = blockIdx.x, l = threadIdx.x;
    ETg[m * L_ + l] = f2bf(__expf(trans[l * L_ + m]));
}

// ---------------------------------------------------------------------------
// Kernel B: labels from one-hot y_true (one wave per row)
// ---------------------------------------------------------------------------
__global__ __launch_bounds__(256) void k_labels(const float* __restrict__ y_true,
                                                int* __restrict__ labels) {
    int wid = threadIdx.x >> 6, lane = threadIdx.x & 63;
    int r = blockIdx.x * 4 + wid;
    const float4* row = (const float4*)(y_true + (size_t)r * L_);
    float4 v = row[lane];
    int loc = -1;
    if (v.x > 0.5f) loc = lane * 4 + 0;
    if (v.y > 0.5f) loc = lane * 4 + 1;
    if (v.z > 0.5f) loc = lane * 4 + 2;
    if (v.w > 0.5f) loc = lane * 4 + 3;
    unsigned long long m = __ballot(loc >= 0);
    int src = __ffsll(m) - 1;
    int lab = __shfl(loc, src, 64);
    if (lane == 0) labels[r] = lab;
}

// ---------------------------------------------------------------------------
// Kernel C: path_score
// ---------------------------------------------------------------------------
__global__ __launch_bounds__(256) void k_path(const float* __restrict__ y_pre,
                                              const float* __restrict__ trans,
                                              const int* __restrict__ labels,
                                              float* __restrict__ path) {
    int b = blockIdx.x, tid = threadIdx.x;
    const int* lb = labels + b * T_;
    float acc = 0.f;
    for (int t = tid; t < T_; t += 256) {
        int l1 = lb[t];
        acc += y_pre[((size_t)b * T_ + t) * L_ + l1];
        if (t + 1 < T_) acc += trans[l1 * L_ + lb[t + 1]];
    }
#pragma unroll
    for (int off = 1; off < 64; off <<= 1) acc += __shfl_xor(acc, off, 64);
    __shared__ float red[4];
    int wid = tid >> 6, lane = tid & 63;
    if (lane == 0) red[wid] = acc;
    __syncthreads();
    if (tid == 0) path[b] = red[0] + red[1] + red[2] + red[3];
}

// ---------------------------------------------------------------------------
// Kernel D: forward recursion, 4-way l-split.
// amdgpu_waves_per_eu(1,1): clamp the occupancy target to 1 wave/EU so the
// register allocator uses the full 512-VGPR budget and keeps the 128-VGPR
// ET block RESIDENT (launch_bounds(256,1) is only a MIN and was ignored:
// rounds 2-3 came back with 140/84 VGPRs and re-fetched ET from L2 every
// step — that refetch was the whole bottleneck).
// ---------------------------------------------------------------------------
__global__ void
__attribute__((amdgpu_flat_work_group_size(256, 256), amdgpu_waves_per_eu(1, 1)))
k_forward(const float* __restrict__ yp_all,
          const unsigned short* __restrict__ ETg,
          const float* __restrict__ path,
          float* __restrict__ out) {
    int b = blockIdx.x, tid = threadIdx.x;
    int c = tid >> 6;          // wave id = l-chunk
    int i = tid & 63;          // lane
    int m_own = (c << 6) | i;
    const float* yp = yp_all + (size_t)b * T_ * L_;

    // 4 row-chunks -> 32 uint4 = 128 VGPRs
    uint4 R[4][8];
#pragma unroll
    for (int r = 0; r < 4; ++r) {
        const uint4* src = (const uint4*)(ETg + (size_t)(i + 64 * r) * L_ + 64 * c);
#pragma unroll
        for (int j = 0; j < 8; ++j) R[r][j] = src[j];
    }
#pragma unroll
    for (int r = 0; r < 4; ++r)
#pragma unroll
        for (int j = 0; j < 8; ++j)
            asm("" : "+v"(R[r][j].x), "+v"(R[r][j].y), "+v"(R[r][j].z), "+v"(R[r][j].w));

    __shared__ unsigned short ph[2][L_];   // p (bf16), double-buffered
    __shared__ float pj[L_ * 5];           // partials, padded stride 5 dwords
    __shared__ float red[4];
    __shared__ float nmr[2];               // sampled normalizer, 2 slots

    float s = yp[m_own];                   // s_0 = y_pre[b,0,:]

    {   // exact initial max (once)
        float v = s;
#pragma unroll
        for (int off = 1; off < 64; off <<= 1) v = fmaxf(v, __shfl_xor(v, off, 64));
        if (i == 0) red[c] = v;
        __syncthreads();
        if (tid == 0) {
            float M = fmaxf(fmaxf(red[0], red[1]), fmaxf(red[2], red[3]));
            nmr[0] = M; nmr[1] = M;
        }
        __syncthreads();
    }

    // emit prefetched TWO steps ahead (HBM miss latency ~900cy > step ~500cy)
    float emit   = yp[(size_t)1 * L_ + m_own];   // for t=1
    float emit1  = yp[(size_t)2 * L_ + m_own];   // for t=2

    for (int t = 1; t < T_; ++t) {
        // ---- phase A ----
        float N = nmr[t & 1];              // broadcast read (lag-2 sample)
        int tpf = (t + 3 <= T_ - 1) ? (t + 3) : (T_ - 1);
        float emit2 = yp[(size_t)tpf * L_ + m_own];   // for t+2
        ph[t & 1][m_own] = f2bf(__expf(s - N));
        __syncthreads();                   // barrier 1: p visible

        // ---- phase B: 4 partial dots over own l-chunk ----
        const uint4* P = (const uint4*)(&ph[t & 1][c << 6]);
        float a0 = 0, a1 = 0, a2 = 0, a3 = 0;
        float b0 = 0, b1 = 0, b2 = 0, b3 = 0;
#pragma unroll
        for (int j = 0; j < 8; ++j) {
            uint4 Pv = P[j];               // uniform b128 (128-B chunk)
            a0 = dot2bf16(Pv.x, R[0][j].x, a0); b0 = dot2bf16(Pv.y, R[0][j].y, b0);
            a0 = dot2bf16(Pv.z, R[0][j].z, a0); b0 = dot2bf16(Pv.w, R[0][j].w, b0);
            a1 = dot2bf16(Pv.x, R[1][j].x, a1); b1 = dot2bf16(Pv.y, R[1][j].y, b1);
            a1 = dot2bf16(Pv.z, R[1][j].z, a1); b1 = dot2bf16(Pv.w, R[1][j].w, b1);
            a2 = dot2bf16(Pv.x, R[2][j].x, a2); b2 = dot2bf16(Pv.y, R[2][j].y, b2);
            a2 = dot2bf16(Pv.z, R[2][j].z, a2); b2 = dot2bf16(Pv.w, R[2][j].w, b2);
            a3 = dot2bf16(Pv.x, R[3][j].x, a3); b3 = dot2bf16(Pv.y, R[3][j].y, b3);
            a3 = dot2bf16(Pv.z, R[3][j].z, a3); b3 = dot2bf16(Pv.w, R[3][j].w, b3);
        }
        pj[(i      ) * 5 + c] = a0 + b0;
        pj[(i +  64) * 5 + c] = a1 + b1;
        pj[(i + 128) * 5 + c] = a2 + b2;
        pj[(i + 192) * 5 + c] = a3 + b3;
        __syncthreads();                   // barrier 2: partials visible

        // ---- phase C: combine, advance state ----
        int base = m_own * 5;
        float sum = (pj[base] + pj[base + 1]) + (pj[base + 2] + pj[base + 3]);
        s = N + __logf(sum) + emit;
        emit = emit1; emit1 = emit2;
        if (tid == 0) nmr[t & 1] = s;      // sample for step t+2
    }

    // final logsumexp over m
    __syncthreads();
    float v = s;
#pragma unroll
    for (int off = 1; off < 64; off <<= 1) v = fmaxf(v, __shfl_xor(v, off, 64));
    if (i == 0) red[c] = v;
    __syncthreads();
    float M = fmaxf(fmaxf(red[0], red[1]), fmaxf(red[2], red[3]));
    float e = __expf(s - M);
    v = e;
#pragma unroll
    for (int off = 1; off < 64; off <<= 1) v += __shfl_xor(v, off, 64);
    __syncthreads();
    if (i == 0) red[c] = v;
    __syncthreads();
    if (tid == 0) out[b] = M + __logf(red[0] + red[1] + red[2] + red[3]) - path[b];
}

// ---------------------------------------------------------------------------
extern "C" void kernel_launch(void* const* d_in, const int* in_sizes, int n_in,
                              void* d_out, int out_size, void* d_ws, size_t ws_size,
                              hipStream_t stream) {
    const float* y_true = (const float*)d_in[0];
    const float* y_pre  = (const float*)d_in[1];
    const float* trans  = (const float*)d_in[2];
    float* out = (float*)d_out;

    char* ws = (char*)d_ws;
    unsigned short* ETg = (unsigned short*)ws;            // 128 KiB
    int* labels = (int*)(ws + 131072);                    // 256 KiB
    float* path = (float*)(ws + 131072 + 262144);         // 512 B

    hipLaunchKernelGGL(k_exptrans, dim3(L_), dim3(L_), 0, stream, trans, ETg);
    hipLaunchKernelGGL(k_labels, dim3(B_ * T_ / 4), dim3(256), 0, stream, y_true, labels);
    hipLaunchKernelGGL(k_path, dim3(B_), dim3(256), 0, stream, y_pre, trans, labels, path);
    hipLaunchKernelGGL(k_forward, dim3(B_), dim3(256), 0, stream, y_pre, ETg, path, out);
}